// Round 6
// baseline (569.692 us; speedup 1.0000x reference)
//
#include <hip/hip_runtime.h>
#include <math.h>

#define N_NODES 50000
#define N_EDGES 1600000
#define NODE_DIM 64
#define HID 16

typedef _Float16 h8 __attribute__((ext_vector_type(8)));

// ---------------- Pass 1: per-dst degree count (L2-resident atomics, ~32/counter)
__global__ void count_kernel(const int* __restrict__ ei, int* __restrict__ gcount) {
    long i = (long)blockIdx.x * blockDim.x + threadIdx.x;
    if (i < N_EDGES) atomicAdd(&gcount[ei[N_EDGES + i]], 1);
}

// ---------------- Pass 2: exclusive scan of 50k counts, single block of 1024.
// Writes dstbeg[0..N] and re-seeds gcount[i] = dstbeg[i] (placement cursor).
__global__ void scan_kernel(int* __restrict__ gcount, int* __restrict__ dstbeg) {
    __shared__ int part[1024];
    int t = threadIdx.x;
    const int C = (N_NODES + 1023) / 1024;   // 49 elements per thread
    int base = t * C;
    int s = 0;
    for (int k = 0; k < C; k++) {
        int i = base + k;
        if (i < N_NODES) s += gcount[i];
    }
    part[t] = s;
    __syncthreads();
    for (int o = 1; o < 1024; o <<= 1) {     // Hillis-Steele inclusive
        int v = (t >= o) ? part[t - o] : 0;
        __syncthreads();
        part[t] += v;
        __syncthreads();
    }
    int run = part[t] - s;                   // exclusive prefix of this chunk
    for (int k = 0; k < C; k++) {
        int i = base + k;
        if (i < N_NODES) {
            int c = gcount[i];
            dstbeg[i] = run;
            gcount[i] = run;                 // cursor starts at dstbeg
            run += c;
        }
    }
    if (t == 1023) dstbeg[N_NODES] = part[1023];
}

// ---------------- Pass 3: place src ids into dst-sorted flat csr (ushort).
__global__ void place_kernel(const int* __restrict__ ei, int* __restrict__ cursor,
                             unsigned short* __restrict__ csr) {
    long i = (long)blockIdx.x * blockDim.x + threadIdx.x;
    if (i >= N_EDGES) return;
    int s = ei[i], d = ei[N_EDGES + i];
    int pos = atomicAdd(&cursor[d], 1);
    csr[pos] = (unsigned short)s;            // src < 50000 < 65536
}

// ---------------- Layer-1 node kernel: h = node_emb @ W1 (weights via s_load)
__global__ void node_h64(const float* __restrict__ x,    // [N,64] f32
                         const float* __restrict__ W,    // [64,16]
                         const float* __restrict__ a_src,
                         const float* __restrict__ a_dst,
                         float* __restrict__ h,          // [N,16]
                         float* __restrict__ as_, float* __restrict__ ad_) {
    int t = threadIdx.x;
    int n = blockIdx.x * blockDim.x + t;
    if (n >= N_NODES) return;
    float acc[HID];
#pragma unroll
    for (int j = 0; j < HID; j++) acc[j] = 0.f;
    const float4* xr = (const float4*)(x + (size_t)n * NODE_DIM);
#pragma unroll
    for (int k4 = 0; k4 < NODE_DIM / 4; k4++) {
        float4 xv = xr[k4];
        const float* w0 = W + (k4 * 4) * HID;   // uniform -> s_load
#pragma unroll
        for (int j = 0; j < HID; j++)
            acc[j] += xv.x * w0[j] + xv.y * w0[HID + j] + xv.z * w0[2 * HID + j] + xv.w * w0[3 * HID + j];
    }
    float s = 0.f, d = 0.f;
#pragma unroll
    for (int j = 0; j < HID; j++) {
        h[(size_t)n * HID + j] = acc[j];
        s += acc[j] * a_src[j];
        d += acc[j] * a_dst[j];
    }
    as_[n] = s; ad_[n] = d;
}

// ---------------- Batched gather core (macro-free via always_inline helper).
// 32 lanes per dst: two 16-lane halves split the edge list. Within a half,
// BATCHES of 16 edges: lane j loads row[base+j] (coalesced, 1 req/16 edges),
// computes ONE exp for its own edge (16x VALU dedup), accumulates den
// per-lane; the per-edge h-FMA broadcasts (s,e) via two shuffles.
__device__ __forceinline__ void gather_core(
        const unsigned short* __restrict__ row, int lo, int hi, int j,
        const float* __restrict__ h, const float* __restrict__ as_, float adn,
        float& acc, float& den) {
    for (int base = lo; base < hi; base += 16) {
        int nb = hi - base; if (nb > 16) nb = 16;
        int idx = base + j;
        int sj = 0;
        float ej = 0.f;
        if (idx < hi) {
            sj = row[idx];
            float lg = as_[sj] + adn;
            lg = lg > 0.f ? lg : 0.2f * lg;
            ej = expf(lg);
        }
        den += ej;
        int e = 0;
        for (; e + 2 <= nb; e += 2) {
            int s0 = __shfl(sj, e, 16),     s1 = __shfl(sj, e + 1, 16);
            float w0 = __shfl(ej, e, 16),   w1 = __shfl(ej, e + 1, 16);
            float h0 = h[(size_t)s0 * HID + j];
            float h1 = h[(size_t)s1 * HID + j];
            acc += w0 * h0 + w1 * h1;
        }
        if (e < nb) {
            int s0 = __shfl(sj, e, 16);
            float w0 = __shfl(ej, e, 16);
            acc += w0 * h[(size_t)s0 * HID + j];
        }
    }
}

// ---------------- Fused layer-1 gather + node_h16 (h2 = x1@W2, as2/ad2).
__global__ void gather1_fused(const int* __restrict__ dstbeg,
                              const unsigned short* __restrict__ csr,
                              const float* __restrict__ h,
                              const float* __restrict__ as_, const float* __restrict__ ad_,
                              const float* __restrict__ b,      // b1
                              const float* __restrict__ W2,     // [16,16]
                              const float* __restrict__ a_src2,
                              const float* __restrict__ a_dst2,
                              float* __restrict__ h2out,        // [N,16]
                              float* __restrict__ as2, float* __restrict__ ad2) {
    int t = threadIdx.x;
    int j = t & 15;
    int half = (t >> 4) & 1;
    float Wcol[HID];
#pragma unroll
    for (int k = 0; k < HID; k++) Wcol[k] = W2[k * HID + j];
    float a2j = a_src2[j], d2j = a_dst2[j], bj = b[j];
    int g = blockIdx.x * (blockDim.x >> 5) + (t >> 5);
    if (g >= N_NODES) return;
    int beg = dstbeg[g], end = dstbeg[g + 1];
    const unsigned short* row = csr + beg;
    int cnt = end - beg;
    int ch = (cnt + 1) >> 1;
    int lo = half ? ch : 0;
    int hi = half ? cnt : ch;
    float adn = ad_[g];
    float acc = 0.f, den = 0.f;
    gather_core(row, lo, hi, j, h, as_, adn, acc, den);
    // den: per-lane partial -> sum within 16, then combine halves
#pragma unroll
    for (int o = 1; o < 16; o <<= 1) den += __shfl_xor(den, o, 16);
    acc += __shfl_xor(acc, 16, 32);
    den += __shfl_xor(den, 16, 32);
    // self-loop
    float lg = as_[g] + adn;
    lg = lg > 0.f ? lg : 0.2f * lg;
    float e = expf(lg);
    den += e;
    acc += e * h[(size_t)g * HID + j];
    float v = acc / den + bj;
    v = 0.5f * v * (1.f + erff(v * 0.70710678118654752f));   // x1[g][j]
    // fused node_h16: h2_j = sum_k x1_k * W2[k][j]
    float acc2 = 0.f;
#pragma unroll
    for (int k2 = 0; k2 < HID; k2++) {
        float xk = __shfl(v, k2, 16);
        acc2 += xk * Wcol[k2];
    }
    float ps = acc2 * a2j, pd = acc2 * d2j;
#pragma unroll
    for (int o = 1; o < 16; o <<= 1) {
        ps += __shfl_xor(ps, o, 16);
        pd += __shfl_xor(pd, o, 16);
    }
    if (half == 0) {
        h2out[(size_t)g * HID + j] = acc2;
        if (j == 0) { as2[g] = ps; ad2[g] = pd; }
    }
}

// ---------------- Fused layer-2 gather + edge_prep (A/B fp16, L2-resident).
__global__ void gather2_fused(const int* __restrict__ dstbeg,
                              const unsigned short* __restrict__ csr,
                              const float* __restrict__ h,
                              const float* __restrict__ as_, const float* __restrict__ ad_,
                              const float* __restrict__ b,      // b2
                              const float* __restrict__ Wm1,    // [48,16] rows 0..31
                              const float* __restrict__ bm1,
                              _Float16* __restrict__ A, _Float16* __restrict__ B) {
    int t = threadIdx.x;
    int j = t & 15;
    int half = (t >> 4) & 1;
    float WaC[HID], WbC[HID];
#pragma unroll
    for (int k = 0; k < HID; k++) {
        WaC[k] = Wm1[k * HID + j];
        WbC[k] = Wm1[HID * HID + k * HID + j];
    }
    float bj = b[j], b1j = bm1[j];
    int g = blockIdx.x * (blockDim.x >> 5) + (t >> 5);
    if (g >= N_NODES) return;
    int beg = dstbeg[g], end = dstbeg[g + 1];
    const unsigned short* row = csr + beg;
    int cnt = end - beg;
    int ch = (cnt + 1) >> 1;
    int lo = half ? ch : 0;
    int hi = half ? cnt : ch;
    float adn = ad_[g];
    float acc = 0.f, den = 0.f;
    gather_core(row, lo, hi, j, h, as_, adn, acc, den);
#pragma unroll
    for (int o = 1; o < 16; o <<= 1) den += __shfl_xor(den, o, 16);
    acc += __shfl_xor(acc, 16, 32);
    den += __shfl_xor(den, 16, 32);
    // self-loop
    float lg = as_[g] + adn;
    lg = lg > 0.f ? lg : 0.2f * lg;
    float e = expf(lg);
    den += e;
    acc += e * h[(size_t)g * HID + j];
    float v = acc / den + bj;
    v = 0.5f * v * (1.f + erff(v * 0.70710678118654752f));   // x2[g][j]
    // fused edge_prep: A = x2@Wm1[0:16]+bm1, B = x2@Wm1[16:32]
    float accA = b1j, accB = 0.f;
#pragma unroll
    for (int k2 = 0; k2 < HID; k2++) {
        float xk = __shfl(v, k2, 16);
        accA += xk * WaC[k2];
        accB += xk * WbC[k2];
    }
    if (half == 0) {
        A[(size_t)g * HID + j] = (_Float16)accA;
        B[(size_t)g * HID + j] = (_Float16)accB;
    }
}

// ---------------- Final per-edge MLP (weights via s_load; fp16 A/B gathers L2-hit)
__global__ void edge_mlp(const int* __restrict__ ei,
                         const _Float16* __restrict__ A, // [N,16] fp16
                         const _Float16* __restrict__ B, // [N,16] fp16
                         const float* __restrict__ ee,   // [E,16] f32
                         const float* __restrict__ Wm1,  // [48,16] (rows 32..47)
                         const float* __restrict__ Wm2,  // [16,1]
                         const float* __restrict__ bm2,  // [1]
                         float* __restrict__ out) {
    int t = threadIdx.x;
    long i = (long)blockIdx.x * blockDim.x + t;
    if (i >= N_EDGES) return;
    int s = ei[i], d = ei[N_EDGES + i];
    const h8* Ap = (const h8*)(A + (size_t)s * HID);
    const h8* Bp = (const h8*)(B + (size_t)d * HID);
    h8 a0 = Ap[0], a1 = Ap[1];
    h8 b0 = Bp[0], b1 = Bp[1];
    const float4* ep = (const float4*)(ee + (size_t)i * HID);
    float4 e0 = ep[0], e1 = ep[1], e2 = ep[2], e3 = ep[3];
    float a[HID];
#pragma unroll
    for (int j = 0; j < 8; j++) {
        a[j]     = (float)a0[j] + (float)b0[j];
        a[8 + j] = (float)a1[j] + (float)b1[j];
    }
    float ev[HID];
    ev[0]  = e0.x; ev[1]  = e0.y; ev[2]  = e0.z; ev[3]  = e0.w;
    ev[4]  = e1.x; ev[5]  = e1.y; ev[6]  = e1.z; ev[7]  = e1.w;
    ev[8]  = e2.x; ev[9]  = e2.y; ev[10] = e2.z; ev[11] = e2.w;
    ev[12] = e3.x; ev[13] = e3.y; ev[14] = e3.z; ev[15] = e3.w;
    const float4* W4 = (const float4*)(Wm1 + 2 * HID * HID);  // uniform -> s_load
#pragma unroll
    for (int k = 0; k < HID; k++) {
        float e1v = ev[k];
        float4 w0 = W4[k * 4 + 0], w1 = W4[k * 4 + 1], w2 = W4[k * 4 + 2], w3 = W4[k * 4 + 3];
        a[0]  += e1v * w0.x; a[1]  += e1v * w0.y; a[2]  += e1v * w0.z; a[3]  += e1v * w0.w;
        a[4]  += e1v * w1.x; a[5]  += e1v * w1.y; a[6]  += e1v * w1.z; a[7]  += e1v * w1.w;
        a[8]  += e1v * w2.x; a[9]  += e1v * w2.y; a[10] += e1v * w2.z; a[11] += e1v * w2.w;
        a[12] += e1v * w3.x; a[13] += e1v * w3.y; a[14] += e1v * w3.z; a[15] += e1v * w3.w;
    }
    float o = bm2[0];
#pragma unroll
    for (int j = 0; j < HID; j++) o += fmaxf(a[j], 0.f) * Wm2[j];
    out[i] = 1.f / (1.f + expf(-o));
}

extern "C" void kernel_launch(void* const* d_in, const int* in_sizes, int n_in,
                              void* d_out, int out_size, void* d_ws, size_t ws_size,
                              hipStream_t stream) {
    const int*   ei       = (const int*)d_in[0];
    const float* node_emb = (const float*)d_in[1];
    const float* edge_emb = (const float*)d_in[2];
    const float* W1       = (const float*)d_in[3];
    const float* att_src1 = (const float*)d_in[4];
    const float* att_dst1 = (const float*)d_in[5];
    const float* b1       = (const float*)d_in[6];
    const float* W2       = (const float*)d_in[7];
    const float* att_src2 = (const float*)d_in[8];
    const float* att_dst2 = (const float*)d_in[9];
    const float* b2       = (const float*)d_in[10];
    const float* Wm1      = (const float*)d_in[11];
    const float* bm1      = (const float*)d_in[12];
    const float* Wm2      = (const float*)d_in[13];
    const float* bm2      = (const float*)d_in[14];
    float* out            = (float*)d_out;

    // ---- workspace carve-up (~14 MB)
    char* w = (char*)d_ws;
    float*          h      = (float*)w;          w += (size_t)N_NODES * HID * 4;       // 3.2 MB
    float*          h2     = (float*)w;          w += (size_t)N_NODES * HID * 4;       // 3.2 MB
    float*          as_    = (float*)w;          w += (size_t)N_NODES * 4;
    float*          ad_    = (float*)w;          w += (size_t)N_NODES * 4;
    float*          as2    = (float*)w;          w += (size_t)N_NODES * 4;
    float*          ad2    = (float*)w;          w += (size_t)N_NODES * 4;
    int*            gcount = (int*)w;            w += (size_t)N_NODES * 4;             // count/cursor
    int*            dstbeg = (int*)w;            w += (size_t)(N_NODES + 1) * 4;
    unsigned short* csr    = (unsigned short*)w; w += (size_t)N_EDGES * 2;             // 3.2 MB
    w = (char*)(((size_t)w + 15) & ~(size_t)15);
    _Float16*       Anode  = (_Float16*)w;       w += (size_t)N_NODES * HID * 2;       // 1.6 MB
    _Float16*       Bnode  = (_Float16*)w;       w += (size_t)N_NODES * HID * 2;       // 1.6 MB

    const int BT = 256;
    int nblk_node = (N_NODES + BT - 1) / BT;
    int nblk_E    = (N_EDGES + BT - 1) / BT;
    int nblk_g32  = (N_NODES + (BT >> 5) - 1) / (BT >> 5);   // 32 lanes per node

    // ---- CSR build: count -> scan (also seeds cursor) -> place
    hipMemsetAsync(gcount, 0, (size_t)N_NODES * sizeof(int), stream);
    count_kernel<<<nblk_E, BT, 0, stream>>>(ei, gcount);
    scan_kernel<<<1, 1024, 0, stream>>>(gcount, dstbeg);
    place_kernel<<<nblk_E, BT, 0, stream>>>(ei, gcount, csr);

    // ---- Layer 1 (+fused node_h16)
    node_h64<<<nblk_node, BT, 0, stream>>>(node_emb, W1, att_src1, att_dst1, h, as_, ad_);
    gather1_fused<<<nblk_g32, BT, 0, stream>>>(dstbeg, csr, h, as_, ad_, b1,
                                               W2, att_src2, att_dst2, h2, as2, ad2);

    // ---- Layer 2 gather (+fused edge_prep)
    gather2_fused<<<nblk_g32, BT, 0, stream>>>(dstbeg, csr, h2, as2, ad2, b2,
                                               Wm1, bm1, Anode, Bnode);

    // ---- Edge MLP
    edge_mlp<<<nblk_E, BT, 0, stream>>>(ei, Anode, Bnode, edge_emb, Wm1, Wm2, bm2, out);
}

// Round 7
// 376.383 us; speedup vs baseline: 1.5136x; 1.5136x over previous
//
#include <hip/hip_runtime.h>
#include <math.h>
#include <string.h>

#define N_NODES 50000
#define N_EDGES 1600000
#define NODE_DIM 64
#define HID 16
#define BSZ 64                                // dsts per bucket
#define NBUCK ((N_NODES + BSZ - 1) / BSZ)     // 782
#define CAPB 2560                             // mean 2046, sd ~45 -> 11 sigma headroom
#define EPB 2048                              // edges per append block (782 blocks)
#define APB 256
#define APPEND_BLOCKS ((N_EDGES + EPB - 1) / EPB)   // 782
#define RECW 16                               // dwords per 64B node record

typedef _Float16 h8 __attribute__((ext_vector_type(8)));

__device__ __forceinline__ float half_from_word(unsigned int w, int hi) {
    unsigned short us = hi ? (unsigned short)(w >> 16) : (unsigned short)(w & 0xffffu);
    _Float16 hv;
    __builtin_memcpy(&hv, &us, 2);
    return (float)hv;
}
__device__ __forceinline__ unsigned int pack_half2(float a, float b) {
    _Float16 ha = (_Float16)a, hb = (_Float16)b;
    unsigned short ua, ub;
    __builtin_memcpy(&ua, &ha, 2);
    __builtin_memcpy(&ub, &hb, 2);
    return (unsigned int)ua | ((unsigned int)ub << 16);
}
__device__ __forceinline__ unsigned short half_bits(float a) {
    _Float16 ha = (_Float16)a;
    unsigned short ua;
    __builtin_memcpy(&ua, &ha, 2);
    return ua;
}

// ---------------- Aggregated append (round-4 proven, ~57us incl. sort):
// 1 global atomic per (block,bucket), not per edge.
__global__ void append_kernel(const int* __restrict__ ei,
                              int* __restrict__ gcount,           // [NBUCK] pre-zeroed
                              unsigned int* __restrict__ blist) { // [NBUCK, CAPB]
    __shared__ int lcount[NBUCK];
    __shared__ int gbase[NBUCK];
    __shared__ int loff[NBUCK];
    int t = threadIdx.x;
    for (int b = t; b < NBUCK; b += APB) { lcount[b] = 0; loff[b] = 0; }
    __syncthreads();
    long base = (long)blockIdx.x * EPB;
#pragma unroll
    for (int k = 0; k < EPB / APB; k++) {
        long i = base + k * APB + t;
        if (i < N_EDGES) atomicAdd(&lcount[ei[N_EDGES + i] >> 6], 1);
    }
    __syncthreads();
    for (int b = t; b < NBUCK; b += APB) {
        int c = lcount[b];
        gbase[b] = c ? atomicAdd(&gcount[b], c) : 0;
    }
    __syncthreads();
#pragma unroll
    for (int k = 0; k < EPB / APB; k++) {
        long i = base + k * APB + t;
        if (i < N_EDGES) {
            int s = ei[i], d = ei[N_EDGES + i];
            int b = d >> 6;
            int pos = gbase[b] + atomicAdd(&loff[b], 1);
            if (pos < CAPB)
                blist[(size_t)b * CAPB + pos] = ((unsigned)(d & 63) << 16) | (unsigned)s;
        }
    }
}

// ---------------- Per-bucket counting sort by dloc -> per-dst-contiguous ushort CSR.
__global__ void sort_kernel(const int* __restrict__ gcount, const unsigned int* __restrict__ blist,
                            unsigned short* __restrict__ csr, int* __restrict__ dstbeg) {
    __shared__ int cnts[BSZ];
    __shared__ int sc[BSZ];
    __shared__ int off[BSZ];
    int b = blockIdx.x, t = threadIdx.x;
    if (t < BSZ) cnts[t] = 0;
    __syncthreads();
    int cnt = gcount[b]; if (cnt > CAPB) cnt = CAPB;
    const unsigned int* lp = blist + (size_t)b * CAPB;
    for (int k = t; k < cnt; k += APB) atomicAdd(&cnts[lp[k] >> 16], 1);
    __syncthreads();
    if (t < BSZ) sc[t] = cnts[t];
    __syncthreads();
    for (int o = 1; o < BSZ; o <<= 1) {          // Hillis-Steele inclusive scan
        int v = 0;
        if (t < BSZ && t >= o) v = sc[t - o];
        __syncthreads();
        if (t < BSZ) sc[t] += v;
        __syncthreads();
    }
    if (t < BSZ) {
        int beg = sc[t] - cnts[t];               // exclusive
        off[t] = beg;
        dstbeg[(b << 6) + t] = beg;
    }
    __syncthreads();
    for (int k = t; k < cnt; k += APB) {
        unsigned int r = lp[k];
        int pos = atomicAdd(&off[r >> 16], 1);
        csr[(size_t)b * CAPB + pos] = (unsigned short)(r & 0xFFFF);
    }
}

// ---------------- Layer-1 node kernel -> packed 64B record:
// rec[n] = { h16[0..15] (32B), as f32 (dw8), ad f32 (dw9), pad }
// One gather edge then costs ONE 64B-line request instead of two.
__global__ void node_h64(const float* __restrict__ x,    // [N,64] f32
                         const float* __restrict__ W,    // [64,16]
                         const float* __restrict__ a_src,
                         const float* __restrict__ a_dst,
                         unsigned int* __restrict__ rec) {
    int t = threadIdx.x;
    int n = blockIdx.x * blockDim.x + t;
    if (n >= N_NODES) return;
    float acc[HID];
#pragma unroll
    for (int j = 0; j < HID; j++) acc[j] = 0.f;
    const float4* xr = (const float4*)(x + (size_t)n * NODE_DIM);
#pragma unroll
    for (int k4 = 0; k4 < NODE_DIM / 4; k4++) {
        float4 xv = xr[k4];
        const float* w0 = W + (k4 * 4) * HID;   // uniform -> s_load
#pragma unroll
        for (int j = 0; j < HID; j++)
            acc[j] += xv.x * w0[j] + xv.y * w0[HID + j] + xv.z * w0[2 * HID + j] + xv.w * w0[3 * HID + j];
    }
    float s = 0.f, d = 0.f;
#pragma unroll
    for (int j = 0; j < HID; j++) {
        s += acc[j] * a_src[j];
        d += acc[j] * a_dst[j];
    }
    uint4 d0, d1;
    d0.x = pack_half2(acc[0], acc[1]);  d0.y = pack_half2(acc[2], acc[3]);
    d0.z = pack_half2(acc[4], acc[5]);  d0.w = pack_half2(acc[6], acc[7]);
    d1.x = pack_half2(acc[8], acc[9]);  d1.y = pack_half2(acc[10], acc[11]);
    d1.z = pack_half2(acc[12], acc[13]); d1.w = pack_half2(acc[14], acc[15]);
    uint4* rp = (uint4*)(rec + (size_t)n * RECW);
    rp[0] = d0;
    rp[1] = d1;
    rec[(size_t)n * RECW + 8] = __float_as_uint(s);
    rec[(size_t)n * RECW + 9] = __float_as_uint(d);
}

// ---------------- Packed-record gather core: 16 lanes per dst, ONE line
// request per edge. Lane j loads dword min(j,8) of rec[s]; shuffles
// redistribute (h-word from lane j>>1, as from lane 8). All lanes compute
// the same e (redundant VALU is cheaper than more shuffles); den identical
// across lanes, no reduction needed.
__device__ __forceinline__ void gather_rec(
        const unsigned short* __restrict__ row, int cnt, int j, int idx, int hi_sel,
        const unsigned int* __restrict__ rec, float adn,
        float& acc, float& den) {
    int k = 0;
    for (; k + 4 <= cnt; k += 4) {
        int s0 = row[k], s1 = row[k + 1], s2 = row[k + 2], s3 = row[k + 3];
        unsigned int w0 = rec[(size_t)s0 * RECW + idx];
        unsigned int w1 = rec[(size_t)s1 * RECW + idx];
        unsigned int w2 = rec[(size_t)s2 * RECW + idx];
        unsigned int w3 = rec[(size_t)s3 * RECW + idx];
        float a0 = __uint_as_float(__shfl((int)w0, 8, 16));
        float a1 = __uint_as_float(__shfl((int)w1, 8, 16));
        float a2 = __uint_as_float(__shfl((int)w2, 8, 16));
        float a3 = __uint_as_float(__shfl((int)w3, 8, 16));
        float l0 = a0 + adn, l1 = a1 + adn, l2 = a2 + adn, l3 = a3 + adn;
        l0 = l0 > 0.f ? l0 : 0.2f * l0;
        l1 = l1 > 0.f ? l1 : 0.2f * l1;
        l2 = l2 > 0.f ? l2 : 0.2f * l2;
        l3 = l3 > 0.f ? l3 : 0.2f * l3;
        float e0 = expf(l0), e1 = expf(l1), e2 = expf(l2), e3 = expf(l3);
        float h0 = half_from_word((unsigned int)__shfl((int)w0, j >> 1, 16), hi_sel);
        float h1 = half_from_word((unsigned int)__shfl((int)w1, j >> 1, 16), hi_sel);
        float h2 = half_from_word((unsigned int)__shfl((int)w2, j >> 1, 16), hi_sel);
        float h3 = half_from_word((unsigned int)__shfl((int)w3, j >> 1, 16), hi_sel);
        den += (e0 + e1) + (e2 + e3);
        acc += (e0 * h0 + e1 * h1) + (e2 * h2 + e3 * h3);
    }
    for (; k < cnt; k++) {
        int s = row[k];
        unsigned int w = rec[(size_t)s * RECW + idx];
        float a = __uint_as_float(__shfl((int)w, 8, 16));
        float lg = a + adn;
        lg = lg > 0.f ? lg : 0.2f * lg;
        float e = expf(lg);
        float hv = half_from_word((unsigned int)__shfl((int)w, j >> 1, 16), hi_sel);
        den += e;
        acc += e * hv;
    }
}

// ---------------- Fused layer-1 gather + node_h16 -> rec2 (packed layer-2 record)
__global__ void gather1_fused(const int* __restrict__ gcount, const int* __restrict__ dstbeg,
                              const unsigned short* __restrict__ csr,
                              const unsigned int* __restrict__ rec,   // layer-1 records
                              const float* __restrict__ b,      // b1
                              const float* __restrict__ W2,     // [16,16]
                              const float* __restrict__ a_src2,
                              const float* __restrict__ a_dst2,
                              unsigned int* __restrict__ rec2) {
    int t = threadIdx.x;
    int j = t & 15;
    int idx = j < 8 ? j : 8;
    int hi_sel = j & 1;
    float Wcol[HID];
#pragma unroll
    for (int k = 0; k < HID; k++) Wcol[k] = W2[k * HID + j];
    float a2j = a_src2[j], d2j = a_dst2[j], bj = b[j];
    int g = blockIdx.x * (blockDim.x >> 4) + (t >> 4);
    if (g >= N_NODES) return;
    int bk = g >> 6, dl = g & 63;
    int cnt_b = gcount[bk]; if (cnt_b > CAPB) cnt_b = CAPB;
    int beg = dstbeg[g];
    int end = (dl < 63) ? dstbeg[g + 1] : cnt_b;
    if (end > cnt_b) end = cnt_b;
    if (beg > end) beg = end;
    const unsigned short* row = csr + (size_t)bk * CAPB + beg;
    int cnt = end - beg;
    float adn = __uint_as_float(rec[(size_t)g * RECW + 9]);
    float acc = 0.f, den = 0.f;
    gather_rec(row, cnt, j, idx, hi_sel, rec, adn, acc, den);
    // self-loop
    {
        unsigned int wg = rec[(size_t)g * RECW + idx];
        float ag = __uint_as_float(__shfl((int)wg, 8, 16));
        float lg = ag + adn;
        lg = lg > 0.f ? lg : 0.2f * lg;
        float e = expf(lg);
        float hg = half_from_word((unsigned int)__shfl((int)wg, j >> 1, 16), hi_sel);
        den += e;
        acc += e * hg;
    }
    float v = acc / den + bj;
    v = 0.5f * v * (1.f + erff(v * 0.70710678118654752f));   // x1[g][j]
    // fused node_h16: h2_j = sum_k x1_k * W2[k][j]
    float acc2 = 0.f;
#pragma unroll
    for (int k2 = 0; k2 < HID; k2++) {
        float xk = __shfl(v, k2, 16);
        acc2 += xk * Wcol[k2];
    }
    float ps = acc2 * a2j, pd = acc2 * d2j;
#pragma unroll
    for (int o = 1; o < 16; o <<= 1) {
        ps += __shfl_xor(ps, o, 16);
        pd += __shfl_xor(pd, o, 16);
    }
    // write rec2: lane j stores h2[j] fp16; lane 0 stores as2/ad2
    ((unsigned short*)rec2)[(size_t)g * (RECW * 2) + j] = half_bits(acc2);
    if (j == 0) {
        rec2[(size_t)g * RECW + 8] = __float_as_uint(ps);
        rec2[(size_t)g * RECW + 9] = __float_as_uint(pd);
    }
}

// ---------------- Fused layer-2 gather + edge_prep (A/B fp16, L2-resident).
__global__ void gather2_fused(const int* __restrict__ gcount, const int* __restrict__ dstbeg,
                              const unsigned short* __restrict__ csr,
                              const unsigned int* __restrict__ rec2,  // layer-2 records
                              const float* __restrict__ b,      // b2
                              const float* __restrict__ Wm1,    // [48,16] rows 0..31
                              const float* __restrict__ bm1,
                              _Float16* __restrict__ A, _Float16* __restrict__ B) {
    int t = threadIdx.x;
    int j = t & 15;
    int idx = j < 8 ? j : 8;
    int hi_sel = j & 1;
    float WaC[HID], WbC[HID];
#pragma unroll
    for (int k = 0; k < HID; k++) {
        WaC[k] = Wm1[k * HID + j];
        WbC[k] = Wm1[HID * HID + k * HID + j];
    }
    float bj = b[j], b1j = bm1[j];
    int g = blockIdx.x * (blockDim.x >> 4) + (t >> 4);
    if (g >= N_NODES) return;
    int bk = g >> 6, dl = g & 63;
    int cnt_b = gcount[bk]; if (cnt_b > CAPB) cnt_b = CAPB;
    int beg = dstbeg[g];
    int end = (dl < 63) ? dstbeg[g + 1] : cnt_b;
    if (end > cnt_b) end = cnt_b;
    if (beg > end) beg = end;
    const unsigned short* row = csr + (size_t)bk * CAPB + beg;
    int cnt = end - beg;
    float adn = __uint_as_float(rec2[(size_t)g * RECW + 9]);
    float acc = 0.f, den = 0.f;
    gather_rec(row, cnt, j, idx, hi_sel, rec2, adn, acc, den);
    // self-loop
    {
        unsigned int wg = rec2[(size_t)g * RECW + idx];
        float ag = __uint_as_float(__shfl((int)wg, 8, 16));
        float lg = ag + adn;
        lg = lg > 0.f ? lg : 0.2f * lg;
        float e = expf(lg);
        float hg = half_from_word((unsigned int)__shfl((int)wg, j >> 1, 16), hi_sel);
        den += e;
        acc += e * hg;
    }
    float v = acc / den + bj;
    v = 0.5f * v * (1.f + erff(v * 0.70710678118654752f));   // x2[g][j]
    // fused edge_prep: A = x2@Wm1[0:16]+bm1, B = x2@Wm1[16:32]
    float accA = b1j, accB = 0.f;
#pragma unroll
    for (int k2 = 0; k2 < HID; k2++) {
        float xk = __shfl(v, k2, 16);
        accA += xk * WaC[k2];
        accB += xk * WbC[k2];
    }
    A[(size_t)g * HID + j] = (_Float16)accA;
    B[(size_t)g * HID + j] = (_Float16)accB;
}

// ---------------- Final per-edge MLP (round-5 proven 65us; weights via s_load)
__global__ void edge_mlp(const int* __restrict__ ei,
                         const _Float16* __restrict__ A, // [N,16] fp16
                         const _Float16* __restrict__ B, // [N,16] fp16
                         const float* __restrict__ ee,   // [E,16] f32
                         const float* __restrict__ Wm1,  // [48,16] (rows 32..47)
                         const float* __restrict__ Wm2,  // [16,1]
                         const float* __restrict__ bm2,  // [1]
                         float* __restrict__ out) {
    int t = threadIdx.x;
    long i = (long)blockIdx.x * blockDim.x + t;
    if (i >= N_EDGES) return;
    int s = ei[i], d = ei[N_EDGES + i];
    const h8* Ap = (const h8*)(A + (size_t)s * HID);
    const h8* Bp = (const h8*)(B + (size_t)d * HID);
    h8 a0 = Ap[0], a1 = Ap[1];
    h8 b0 = Bp[0], b1 = Bp[1];
    const float4* ep = (const float4*)(ee + (size_t)i * HID);
    float4 e0 = ep[0], e1 = ep[1], e2 = ep[2], e3 = ep[3];
    float a[HID];
#pragma unroll
    for (int j = 0; j < 8; j++) {
        a[j]     = (float)a0[j] + (float)b0[j];
        a[8 + j] = (float)a1[j] + (float)b1[j];
    }
    float ev[HID];
    ev[0]  = e0.x; ev[1]  = e0.y; ev[2]  = e0.z; ev[3]  = e0.w;
    ev[4]  = e1.x; ev[5]  = e1.y; ev[6]  = e1.z; ev[7]  = e1.w;
    ev[8]  = e2.x; ev[9]  = e2.y; ev[10] = e2.z; ev[11] = e2.w;
    ev[12] = e3.x; ev[13] = e3.y; ev[14] = e3.z; ev[15] = e3.w;
    const float4* W4 = (const float4*)(Wm1 + 2 * HID * HID);  // uniform -> s_load
#pragma unroll
    for (int k = 0; k < HID; k++) {
        float e1v = ev[k];
        float4 w0 = W4[k * 4 + 0], w1 = W4[k * 4 + 1], w2 = W4[k * 4 + 2], w3 = W4[k * 4 + 3];
        a[0]  += e1v * w0.x; a[1]  += e1v * w0.y; a[2]  += e1v * w0.z; a[3]  += e1v * w0.w;
        a[4]  += e1v * w1.x; a[5]  += e1v * w1.y; a[6]  += e1v * w1.z; a[7]  += e1v * w1.w;
        a[8]  += e1v * w2.x; a[9]  += e1v * w2.y; a[10] += e1v * w2.z; a[11] += e1v * w2.w;
        a[12] += e1v * w3.x; a[13] += e1v * w3.y; a[14] += e1v * w3.z; a[15] += e1v * w3.w;
    }
    float o = bm2[0];
#pragma unroll
    for (int j = 0; j < HID; j++) o += fmaxf(a[j], 0.f) * Wm2[j];
    out[i] = 1.f / (1.f + expf(-o));
}

extern "C" void kernel_launch(void* const* d_in, const int* in_sizes, int n_in,
                              void* d_out, int out_size, void* d_ws, size_t ws_size,
                              hipStream_t stream) {
    const int*   ei       = (const int*)d_in[0];
    const float* node_emb = (const float*)d_in[1];
    const float* edge_emb = (const float*)d_in[2];
    const float* W1       = (const float*)d_in[3];
    const float* att_src1 = (const float*)d_in[4];
    const float* att_dst1 = (const float*)d_in[5];
    const float* b1       = (const float*)d_in[6];
    const float* W2       = (const float*)d_in[7];
    const float* att_src2 = (const float*)d_in[8];
    const float* att_dst2 = (const float*)d_in[9];
    const float* b2       = (const float*)d_in[10];
    const float* Wm1      = (const float*)d_in[11];
    const float* bm1      = (const float*)d_in[12];
    const float* Wm2      = (const float*)d_in[13];
    const float* bm2      = (const float*)d_in[14];
    float* out            = (float*)d_out;

    // ---- workspace carve-up (~18.8 MB)
    char* w = (char*)d_ws;
    unsigned int*   rec1   = (unsigned int*)w;   w += (size_t)N_NODES * RECW * 4;     // 3.2 MB
    unsigned int*   rec2   = (unsigned int*)w;   w += (size_t)N_NODES * RECW * 4;     // 3.2 MB
    int*            gcount = (int*)w;            w += (size_t)NBUCK * 4;
    unsigned int*   blist  = (unsigned int*)w;   w += (size_t)NBUCK * CAPB * 4;       // 8.0 MB
    unsigned short* csr    = (unsigned short*)w; w += (size_t)NBUCK * CAPB * 2;       // 4.0 MB
    int*            dstbeg = (int*)w;            w += (size_t)NBUCK * BSZ * 4;        // 0.2 MB

    // blist dead after sort_kernel; reuse for fp16 A/B (edge_mlp inputs)
    _Float16* Anode = (_Float16*)blist;
    _Float16* Bnode = Anode + (size_t)N_NODES * HID;

    const int BT = 256;
    int nblk_node = (N_NODES + BT - 1) / BT;
    int nblk_E    = (N_EDGES + BT - 1) / BT;
    int nblk_g    = (N_NODES * HID + BT - 1) / BT;   // 16 lanes per node

    // ---- aggregated build + counting sort (round-4 proven)
    hipMemsetAsync(gcount, 0, (size_t)NBUCK * sizeof(int), stream);
    append_kernel<<<APPEND_BLOCKS, APB, 0, stream>>>(ei, gcount, blist);
    sort_kernel<<<NBUCK, APB, 0, stream>>>(gcount, blist, csr, dstbeg);

    // ---- Layer 1: node transform -> packed records
    node_h64<<<nblk_node, BT, 0, stream>>>(node_emb, W1, att_src1, att_dst1, rec1);
    gather1_fused<<<nblk_g, BT, 0, stream>>>(gcount, dstbeg, csr, rec1, b1,
                                             W2, att_src2, att_dst2, rec2);

    // ---- Layer 2 gather (+fused edge_prep)
    gather2_fused<<<nblk_g, BT, 0, stream>>>(gcount, dstbeg, csr, rec2, b2,
                                             Wm1, bm1, Anode, Bnode);

    // ---- Edge MLP
    edge_mlp<<<nblk_E, BT, 0, stream>>>(ei, Anode, Bnode, edge_emb, Wm1, Wm2, bm2, out);
}

// Round 8
// 353.587 us; speedup vs baseline: 1.6112x; 1.0645x over previous
//
#include <hip/hip_runtime.h>
#include <math.h>
#include <string.h>

#define N_NODES 50000
#define N_EDGES 1600000
#define NODE_DIM 64
#define HID 16
#define BSZ 64                                // dsts per bucket
#define NBUCK ((N_NODES + BSZ - 1) / BSZ)     // 782
#define CAPB 2560                             // mean 2046, sd ~45 -> 11 sigma headroom
#define EPB 2048                              // edges per append block (782 blocks)
#define APB 256
#define APPEND_BLOCKS ((N_EDGES + EPB - 1) / EPB)   // 782

typedef _Float16 h8 __attribute__((ext_vector_type(8)));

__device__ __forceinline__ unsigned short half_bits(float a) {
    _Float16 ha = (_Float16)a;
    unsigned short ua;
    __builtin_memcpy(&ua, &ha, 2);
    return ua;
}
__device__ __forceinline__ float bits_half(unsigned int ub) {
    unsigned short us = (unsigned short)ub;
    _Float16 hv;
    __builtin_memcpy(&hv, &us, 2);
    return (float)hv;
}

// ---------------- Aggregated append (proven ~57us incl. sort)
__global__ void append_kernel(const int* __restrict__ ei,
                              int* __restrict__ gcount,           // [NBUCK] pre-zeroed
                              unsigned int* __restrict__ blist) { // [NBUCK, CAPB]
    __shared__ int lcount[NBUCK];
    __shared__ int gbase[NBUCK];
    __shared__ int loff[NBUCK];
    int t = threadIdx.x;
    for (int b = t; b < NBUCK; b += APB) { lcount[b] = 0; loff[b] = 0; }
    __syncthreads();
    long base = (long)blockIdx.x * EPB;
#pragma unroll
    for (int k = 0; k < EPB / APB; k++) {
        long i = base + k * APB + t;
        if (i < N_EDGES) atomicAdd(&lcount[ei[N_EDGES + i] >> 6], 1);
    }
    __syncthreads();
    for (int b = t; b < NBUCK; b += APB) {
        int c = lcount[b];
        gbase[b] = c ? atomicAdd(&gcount[b], c) : 0;
    }
    __syncthreads();
#pragma unroll
    for (int k = 0; k < EPB / APB; k++) {
        long i = base + k * APB + t;
        if (i < N_EDGES) {
            int s = ei[i], d = ei[N_EDGES + i];
            int b = d >> 6;
            int pos = gbase[b] + atomicAdd(&loff[b], 1);
            if (pos < CAPB)
                blist[(size_t)b * CAPB + pos] = ((unsigned)(d & 63) << 16) | (unsigned)s;
        }
    }
}

// ---------------- Per-bucket counting sort -> per-dst-contiguous ushort CSR.
__global__ void sort_kernel(const int* __restrict__ gcount, const unsigned int* __restrict__ blist,
                            unsigned short* __restrict__ csr, int* __restrict__ dstbeg) {
    __shared__ int cnts[BSZ];
    __shared__ int sc[BSZ];
    __shared__ int off[BSZ];
    int b = blockIdx.x, t = threadIdx.x;
    if (t < BSZ) cnts[t] = 0;
    __syncthreads();
    int cnt = gcount[b]; if (cnt > CAPB) cnt = CAPB;
    const unsigned int* lp = blist + (size_t)b * CAPB;
    for (int k = t; k < cnt; k += APB) atomicAdd(&cnts[lp[k] >> 16], 1);
    __syncthreads();
    if (t < BSZ) sc[t] = cnts[t];
    __syncthreads();
    for (int o = 1; o < BSZ; o <<= 1) {          // Hillis-Steele inclusive scan
        int v = 0;
        if (t < BSZ && t >= o) v = sc[t - o];
        __syncthreads();
        if (t < BSZ) sc[t] += v;
        __syncthreads();
    }
    if (t < BSZ) {
        int beg = sc[t] - cnts[t];               // exclusive (bucket-local)
        off[t] = beg;
        dstbeg[(b << 6) + t] = beg;
    }
    __syncthreads();
    for (int k = t; k < cnt; k += APB) {
        unsigned int r = lp[k];
        int pos = atomicAdd(&off[r >> 16], 1);
        csr[(size_t)b * CAPB + pos] = (unsigned short)(r & 0xFFFF);
    }
}

// ---------------- Layer-1 node kernel: h1 fp16 + as1/ad1 f32 (weights via s_load)
__global__ void node_h64(const float* __restrict__ x,    // [N,64] f32
                         const float* __restrict__ W,    // [64,16]
                         const float* __restrict__ a_src,
                         const float* __restrict__ a_dst,
                         _Float16* __restrict__ h16,     // [N,16] fp16
                         float* __restrict__ as_, float* __restrict__ ad_) {
    int t = threadIdx.x;
    int n = blockIdx.x * blockDim.x + t;
    if (n >= N_NODES) return;
    float acc[HID];
#pragma unroll
    for (int j = 0; j < HID; j++) acc[j] = 0.f;
    const float4* xr = (const float4*)(x + (size_t)n * NODE_DIM);
#pragma unroll
    for (int k4 = 0; k4 < NODE_DIM / 4; k4++) {
        float4 xv = xr[k4];
        const float* w0 = W + (k4 * 4) * HID;   // uniform -> s_load
#pragma unroll
        for (int j = 0; j < HID; j++)
            acc[j] += xv.x * w0[j] + xv.y * w0[HID + j] + xv.z * w0[2 * HID + j] + xv.w * w0[3 * HID + j];
    }
    float s = 0.f, d = 0.f;
#pragma unroll
    for (int j = 0; j < HID; j++) {
        s += acc[j] * a_src[j];
        d += acc[j] * a_dst[j];
    }
    h8 hv0, hv1;
#pragma unroll
    for (int j = 0; j < 8; j++) { hv0[j] = (_Float16)acc[j]; hv1[j] = (_Float16)acc[8 + j]; }
    h8* hp = (h8*)(h16 + (size_t)n * HID);
    hp[0] = hv0; hp[1] = hv1;
    as_[n] = s; ad_[n] = d;
}

// ---------------- Edge-parallel exp pass: hoists the exp/as_-gather chain out
// of the serial gather loop. 16 lanes per dst, lane-parallel over its edges:
// crec[k] = (fp16(e)<<16)|src, den[g] = sum(e) via 4 shuffles. The random
// as_[s] 4B gather is fully latency-hidden at edge-parallel TLP.
__global__ void exp_kernel(const int* __restrict__ gcount, const int* __restrict__ dstbeg,
                           const unsigned short* __restrict__ csr,
                           const float* __restrict__ as_, const float* __restrict__ ad_,
                           unsigned int* __restrict__ crec, float* __restrict__ den) {
    int t = threadIdx.x;
    int j = t & 15;
    int g = blockIdx.x * (blockDim.x >> 4) + (t >> 4);
    if (g >= N_NODES) return;
    int bk = g >> 6, dl = g & 63;
    int cnt_b = gcount[bk]; if (cnt_b > CAPB) cnt_b = CAPB;
    int beg = dstbeg[g];
    int end = (dl < 63) ? dstbeg[g + 1] : cnt_b;
    if (end > cnt_b) end = cnt_b;
    if (beg > end) beg = end;
    const unsigned short* row = csr + (size_t)bk * CAPB;
    unsigned int* cr = crec + (size_t)bk * CAPB;
    float adn = ad_[g];
    float dsum = 0.f;
    for (int k = beg + j; k < end; k += 16) {
        int s = row[k];
        float lg = as_[s] + adn;
        lg = lg > 0.f ? lg : 0.2f * lg;
        float e = expf(lg);
        unsigned short eb = half_bits(e);
        dsum += bits_half(eb);               // den from the SAME rounded e
        cr[k] = ((unsigned)eb << 16) | (unsigned)s;
    }
#pragma unroll
    for (int o = 1; o < 16; o <<= 1) dsum += __shfl_xor(dsum, o, 16);
    if (j == 0) den[g] = dsum;
}

// ---------------- Minimal gather core: per 16 edges, ONE coalesced crec load,
// then 16 x {shuffle, extract, random 32B h-load, FMA}. No exp, no as_,
// no den in the loop.
__device__ __forceinline__ void gather_core(
        const unsigned int* __restrict__ cr, int beg, int end, int j,
        const _Float16* __restrict__ h16, float& acc) {
    int base = beg;
    for (; base + 16 <= end; base += 16) {
        unsigned int c = cr[base + j];
#pragma unroll
        for (int e = 0; e < 16; e += 4) {
            unsigned int c0 = (unsigned)__shfl((int)c, e, 16);
            unsigned int c1 = (unsigned)__shfl((int)c, e + 1, 16);
            unsigned int c2 = (unsigned)__shfl((int)c, e + 2, 16);
            unsigned int c3 = (unsigned)__shfl((int)c, e + 3, 16);
            float h0 = (float)h16[(size_t)(c0 & 0xffffu) * HID + j];
            float h1 = (float)h16[(size_t)(c1 & 0xffffu) * HID + j];
            float h2 = (float)h16[(size_t)(c2 & 0xffffu) * HID + j];
            float h3 = (float)h16[(size_t)(c3 & 0xffffu) * HID + j];
            acc += bits_half(c0 >> 16) * h0 + bits_half(c1 >> 16) * h1
                 + bits_half(c2 >> 16) * h2 + bits_half(c3 >> 16) * h3;
        }
    }
    int nb = end - base;
    if (nb > 0) {
        unsigned int c = (base + j < end) ? cr[base + j] : 0u;
        for (int e = 0; e < nb; e++) {
            unsigned int ce = (unsigned)__shfl((int)c, e, 16);
            acc += bits_half(ce >> 16) * (float)h16[(size_t)(ce & 0xffffu) * HID + j];
        }
    }
}

// ---------------- Fused layer-1 gather + node_h16 -> h2 fp16 + as2/ad2
__global__ void gather1_fused(const int* __restrict__ gcount, const int* __restrict__ dstbeg,
                              const unsigned int* __restrict__ crec,
                              const _Float16* __restrict__ h1,
                              const float* __restrict__ as_, const float* __restrict__ ad_,
                              const float* __restrict__ den,
                              const float* __restrict__ b,      // b1
                              const float* __restrict__ W2,     // [16,16]
                              const float* __restrict__ a_src2,
                              const float* __restrict__ a_dst2,
                              _Float16* __restrict__ h2,
                              float* __restrict__ as2, float* __restrict__ ad2) {
    int t = threadIdx.x;
    int j = t & 15;
    float Wcol[HID];
#pragma unroll
    for (int k = 0; k < HID; k++) Wcol[k] = W2[k * HID + j];
    float a2j = a_src2[j], d2j = a_dst2[j], bj = b[j];
    int g = blockIdx.x * (blockDim.x >> 4) + (t >> 4);
    if (g >= N_NODES) return;
    int bk = g >> 6, dl = g & 63;
    int cnt_b = gcount[bk]; if (cnt_b > CAPB) cnt_b = CAPB;
    int beg = dstbeg[g];
    int end = (dl < 63) ? dstbeg[g + 1] : cnt_b;
    if (end > cnt_b) end = cnt_b;
    if (beg > end) beg = end;
    const unsigned int* cr = crec + (size_t)bk * CAPB;
    float acc = 0.f;
    gather_core(cr, beg, end, j, h1, acc);
    // self-loop
    float adn = ad_[g];
    float lg = as_[g] + adn;
    lg = lg > 0.f ? lg : 0.2f * lg;
    float es = expf(lg);
    float dent = den[g] + es;
    acc += es * (float)h1[(size_t)g * HID + j];
    float v = acc / dent + bj;
    v = 0.5f * v * (1.f + erff(v * 0.70710678118654752f));   // x1[g][j]
    // fused node_h16: h2_j = sum_k x1_k * W2[k][j]
    float acc2 = 0.f;
#pragma unroll
    for (int k2 = 0; k2 < HID; k2++) {
        float xk = __shfl(v, k2, 16);
        acc2 += xk * Wcol[k2];
    }
    float ps = acc2 * a2j, pd = acc2 * d2j;
#pragma unroll
    for (int o = 1; o < 16; o <<= 1) {
        ps += __shfl_xor(ps, o, 16);
        pd += __shfl_xor(pd, o, 16);
    }
    h2[(size_t)g * HID + j] = (_Float16)acc2;
    if (j == 0) { as2[g] = ps; ad2[g] = pd; }
}

// ---------------- Fused layer-2 gather + edge_prep -> A/B fp16 (L2-resident)
__global__ void gather2_fused(const int* __restrict__ gcount, const int* __restrict__ dstbeg,
                              const unsigned int* __restrict__ crec,
                              const _Float16* __restrict__ h2,
                              const float* __restrict__ as_, const float* __restrict__ ad_,
                              const float* __restrict__ den,
                              const float* __restrict__ b,      // b2
                              const float* __restrict__ Wm1,    // [48,16] rows 0..31
                              const float* __restrict__ bm1,
                              _Float16* __restrict__ A, _Float16* __restrict__ B) {
    int t = threadIdx.x;
    int j = t & 15;
    float WaC[HID], WbC[HID];
#pragma unroll
    for (int k = 0; k < HID; k++) {
        WaC[k] = Wm1[k * HID + j];
        WbC[k] = Wm1[HID * HID + k * HID + j];
    }
    float bj = b[j], b1j = bm1[j];
    int g = blockIdx.x * (blockDim.x >> 4) + (t >> 4);
    if (g >= N_NODES) return;
    int bk = g >> 6, dl = g & 63;
    int cnt_b = gcount[bk]; if (cnt_b > CAPB) cnt_b = CAPB;
    int beg = dstbeg[g];
    int end = (dl < 63) ? dstbeg[g + 1] : cnt_b;
    if (end > cnt_b) end = cnt_b;
    if (beg > end) beg = end;
    const unsigned int* cr = crec + (size_t)bk * CAPB;
    float acc = 0.f;
    gather_core(cr, beg, end, j, h2, acc);
    // self-loop
    float adn = ad_[g];
    float lg = as_[g] + adn;
    lg = lg > 0.f ? lg : 0.2f * lg;
    float es = expf(lg);
    float dent = den[g] + es;
    acc += es * (float)h2[(size_t)g * HID + j];
    float v = acc / dent + bj;
    v = 0.5f * v * (1.f + erff(v * 0.70710678118654752f));   // x2[g][j]
    // fused edge_prep: A = x2@Wm1[0:16]+bm1, B = x2@Wm1[16:32]
    float accA = b1j, accB = 0.f;
#pragma unroll
    for (int k2 = 0; k2 < HID; k2++) {
        float xk = __shfl(v, k2, 16);
        accA += xk * WaC[k2];
        accB += xk * WbC[k2];
    }
    A[(size_t)g * HID + j] = (_Float16)accA;
    B[(size_t)g * HID + j] = (_Float16)accB;
}

// ---------------- Final per-edge MLP (proven 65us; weights via s_load)
__global__ void edge_mlp(const int* __restrict__ ei,
                         const _Float16* __restrict__ A, // [N,16] fp16
                         const _Float16* __restrict__ B, // [N,16] fp16
                         const float* __restrict__ ee,   // [E,16] f32
                         const float* __restrict__ Wm1,  // [48,16] (rows 32..47)
                         const float* __restrict__ Wm2,  // [16,1]
                         const float* __restrict__ bm2,  // [1]
                         float* __restrict__ out) {
    int t = threadIdx.x;
    long i = (long)blockIdx.x * blockDim.x + t;
    if (i >= N_EDGES) return;
    int s = ei[i], d = ei[N_EDGES + i];
    const h8* Ap = (const h8*)(A + (size_t)s * HID);
    const h8* Bp = (const h8*)(B + (size_t)d * HID);
    h8 a0 = Ap[0], a1 = Ap[1];
    h8 b0 = Bp[0], b1 = Bp[1];
    const float4* ep = (const float4*)(ee + (size_t)i * HID);
    float4 e0 = ep[0], e1 = ep[1], e2 = ep[2], e3 = ep[3];
    float a[HID];
#pragma unroll
    for (int j = 0; j < 8; j++) {
        a[j]     = (float)a0[j] + (float)b0[j];
        a[8 + j] = (float)a1[j] + (float)b1[j];
    }
    float ev[HID];
    ev[0]  = e0.x; ev[1]  = e0.y; ev[2]  = e0.z; ev[3]  = e0.w;
    ev[4]  = e1.x; ev[5]  = e1.y; ev[6]  = e1.z; ev[7]  = e1.w;
    ev[8]  = e2.x; ev[9]  = e2.y; ev[10] = e2.z; ev[11] = e2.w;
    ev[12] = e3.x; ev[13] = e3.y; ev[14] = e3.z; ev[15] = e3.w;
    const float4* W4 = (const float4*)(Wm1 + 2 * HID * HID);  // uniform -> s_load
#pragma unroll
    for (int k = 0; k < HID; k++) {
        float e1v = ev[k];
        float4 w0 = W4[k * 4 + 0], w1 = W4[k * 4 + 1], w2 = W4[k * 4 + 2], w3 = W4[k * 4 + 3];
        a[0]  += e1v * w0.x; a[1]  += e1v * w0.y; a[2]  += e1v * w0.z; a[3]  += e1v * w0.w;
        a[4]  += e1v * w1.x; a[5]  += e1v * w1.y; a[6]  += e1v * w1.z; a[7]  += e1v * w1.w;
        a[8]  += e1v * w2.x; a[9]  += e1v * w2.y; a[10] += e1v * w2.z; a[11] += e1v * w2.w;
        a[12] += e1v * w3.x; a[13] += e1v * w3.y; a[14] += e1v * w3.z; a[15] += e1v * w3.w;
    }
    float o = bm2[0];
#pragma unroll
    for (int j = 0; j < HID; j++) o += fmaxf(a[j], 0.f) * Wm2[j];
    out[i] = 1.f / (1.f + expf(-o));
}

extern "C" void kernel_launch(void* const* d_in, const int* in_sizes, int n_in,
                              void* d_out, int out_size, void* d_ws, size_t ws_size,
                              hipStream_t stream) {
    const int*   ei       = (const int*)d_in[0];
    const float* node_emb = (const float*)d_in[1];
    const float* edge_emb = (const float*)d_in[2];
    const float* W1       = (const float*)d_in[3];
    const float* att_src1 = (const float*)d_in[4];
    const float* att_dst1 = (const float*)d_in[5];
    const float* b1       = (const float*)d_in[6];
    const float* W2       = (const float*)d_in[7];
    const float* att_src2 = (const float*)d_in[8];
    const float* att_dst2 = (const float*)d_in[9];
    const float* b2       = (const float*)d_in[10];
    const float* Wm1      = (const float*)d_in[11];
    const float* bm1      = (const float*)d_in[12];
    const float* Wm2      = (const float*)d_in[13];
    const float* bm2      = (const float*)d_in[14];
    float* out            = (float*)d_out;

    // ---- workspace carve-up (~19.6 MB)
    char* w = (char*)d_ws;
    _Float16*       h1     = (_Float16*)w;       w += (size_t)N_NODES * HID * 2;      // 1.6 MB
    _Float16*       h2     = (_Float16*)w;       w += (size_t)N_NODES * HID * 2;      // 1.6 MB
    _Float16*       Anode  = (_Float16*)w;       w += (size_t)N_NODES * HID * 2;      // 1.6 MB
    _Float16*       Bnode  = (_Float16*)w;       w += (size_t)N_NODES * HID * 2;      // 1.6 MB
    float*          as1    = (float*)w;          w += (size_t)N_NODES * 4;
    float*          ad1    = (float*)w;          w += (size_t)N_NODES * 4;
    float*          as2    = (float*)w;          w += (size_t)N_NODES * 4;
    float*          ad2    = (float*)w;          w += (size_t)N_NODES * 4;
    float*          den    = (float*)w;          w += (size_t)N_NODES * 4;
    int*            gcount = (int*)w;            w += (size_t)NBUCK * 4;
    unsigned int*   blist  = (unsigned int*)w;   w += (size_t)NBUCK * CAPB * 4;       // 8.0 MB
    unsigned short* csr    = (unsigned short*)w; w += (size_t)NBUCK * CAPB * 2;       // 4.0 MB
    int*            dstbeg = (int*)w;            w += (size_t)NBUCK * BSZ * 4;        // 0.2 MB

    // blist dead after sort -> reuse as crec (same [NBUCK][CAPB] uint shape)
    unsigned int* crec = blist;

    const int BT = 256;
    int nblk_node = (N_NODES + BT - 1) / BT;
    int nblk_E    = (N_EDGES + BT - 1) / BT;
    int nblk_g    = (N_NODES * HID + BT - 1) / BT;   // 16 lanes per node

    // ---- build (proven)
    hipMemsetAsync(gcount, 0, (size_t)NBUCK * sizeof(int), stream);
    append_kernel<<<APPEND_BLOCKS, APB, 0, stream>>>(ei, gcount, blist);
    sort_kernel<<<NBUCK, APB, 0, stream>>>(gcount, blist, csr, dstbeg);

    // ---- Layer 1
    node_h64<<<nblk_node, BT, 0, stream>>>(node_emb, W1, att_src1, att_dst1, h1, as1, ad1);
    exp_kernel<<<nblk_g, BT, 0, stream>>>(gcount, dstbeg, csr, as1, ad1, crec, den);
    gather1_fused<<<nblk_g, BT, 0, stream>>>(gcount, dstbeg, crec, h1, as1, ad1, den, b1,
                                             W2, att_src2, att_dst2, h2, as2, ad2);

    // ---- Layer 2
    exp_kernel<<<nblk_g, BT, 0, stream>>>(gcount, dstbeg, csr, as2, ad2, crec, den);
    gather2_fused<<<nblk_g, BT, 0, stream>>>(gcount, dstbeg, crec, h2, as2, ad2, den, b2,
                                             Wm1, bm1, Anode, Bnode);

    // ---- Edge MLP
    edge_mlp<<<nblk_E, BT, 0, stream>>>(ei, Anode, Bnode, edge_emb, Wm1, Wm2, bm2, out);
}

// Round 9
// 340.290 us; speedup vs baseline: 1.6741x; 1.0391x over previous
//
#include <hip/hip_runtime.h>
#include <math.h>
#include <string.h>

#define N_NODES 50000
#define N_EDGES 1600000
#define NODE_DIM 64
#define HID 16
#define BSZ 64                                // dsts per bucket
#define NBUCK ((N_NODES + BSZ - 1) / BSZ)     // 782
#define CAPB 2560                             // mean 2046, sd ~45 -> 11 sigma headroom
#define EPB 2048                              // edges per append block (782 blocks)
#define APB 256
#define APPEND_BLOCKS ((N_EDGES + EPB - 1) / EPB)   // 782

typedef _Float16 h8 __attribute__((ext_vector_type(8)));

// ---------------- Aggregated append (proven; gcount pre-zeroed by node_h64)
__global__ void append_kernel(const int* __restrict__ ei,
                              int* __restrict__ gcount,
                              unsigned int* __restrict__ blist) { // [NBUCK, CAPB]
    __shared__ int lcount[NBUCK];
    __shared__ int gbase[NBUCK];
    __shared__ int loff[NBUCK];
    int t = threadIdx.x;
    for (int b = t; b < NBUCK; b += APB) { lcount[b] = 0; loff[b] = 0; }
    __syncthreads();
    long base = (long)blockIdx.x * EPB;
#pragma unroll
    for (int k = 0; k < EPB / APB; k++) {
        long i = base + k * APB + t;
        if (i < N_EDGES) atomicAdd(&lcount[ei[N_EDGES + i] >> 6], 1);
    }
    __syncthreads();
    for (int b = t; b < NBUCK; b += APB) {
        int c = lcount[b];
        gbase[b] = c ? atomicAdd(&gcount[b], c) : 0;
    }
    __syncthreads();
#pragma unroll
    for (int k = 0; k < EPB / APB; k++) {
        long i = base + k * APB + t;
        if (i < N_EDGES) {
            int s = ei[i], d = ei[N_EDGES + i];
            int b = d >> 6;
            int pos = gbase[b] + atomicAdd(&loff[b], 1);
            if (pos < CAPB)
                blist[(size_t)b * CAPB + pos] = ((unsigned)(d & 63) << 16) | (unsigned)s;
        }
    }
}

// ---------------- Per-bucket counting sort -> per-dst-contiguous ushort CSR.
__global__ void sort_kernel(const int* __restrict__ gcount, const unsigned int* __restrict__ blist,
                            unsigned short* __restrict__ csr, int* __restrict__ dstbeg) {
    __shared__ int cnts[BSZ];
    __shared__ int sc[BSZ];
    __shared__ int off[BSZ];
    int b = blockIdx.x, t = threadIdx.x;
    if (t < BSZ) cnts[t] = 0;
    __syncthreads();
    int cnt = gcount[b]; if (cnt > CAPB) cnt = CAPB;
    const unsigned int* lp = blist + (size_t)b * CAPB;
    for (int k = t; k < cnt; k += APB) atomicAdd(&cnts[lp[k] >> 16], 1);
    __syncthreads();
    if (t < BSZ) sc[t] = cnts[t];
    __syncthreads();
    for (int o = 1; o < BSZ; o <<= 1) {          // Hillis-Steele inclusive scan
        int v = 0;
        if (t < BSZ && t >= o) v = sc[t - o];
        __syncthreads();
        if (t < BSZ) sc[t] += v;
        __syncthreads();
    }
    if (t < BSZ) {
        int beg = sc[t] - cnts[t];               // exclusive (bucket-local)
        off[t] = beg;
        dstbeg[(b << 6) + t] = beg;
    }
    __syncthreads();
    for (int k = t; k < cnt; k += APB) {
        unsigned int r = lp[k];
        int pos = atomicAdd(&off[r >> 16], 1);
        csr[(size_t)b * CAPB + pos] = (unsigned short)(r & 0xFFFF);
    }
}

// ---------------- Layer-1 node kernel (+ zeroes gcount, replacing the memset
// dispatch; node_h64 fully completes before append in stream order).
__global__ void node_h64(const float* __restrict__ x,    // [N,64] f32
                         const float* __restrict__ W,    // [64,16]
                         const float* __restrict__ a_src,
                         const float* __restrict__ a_dst,
                         _Float16* __restrict__ h16,     // [N,16] fp16
                         float* __restrict__ as_, float* __restrict__ ad_,
                         int* __restrict__ gcount) {
    int t = threadIdx.x;
    int n = blockIdx.x * blockDim.x + t;
    if (n < NBUCK) gcount[n] = 0;
    if (n >= N_NODES) return;
    float acc[HID];
#pragma unroll
    for (int j = 0; j < HID; j++) acc[j] = 0.f;
    const float4* xr = (const float4*)(x + (size_t)n * NODE_DIM);
#pragma unroll
    for (int k4 = 0; k4 < NODE_DIM / 4; k4++) {
        float4 xv = xr[k4];
        const float* w0 = W + (k4 * 4) * HID;   // uniform -> s_load
#pragma unroll
        for (int j = 0; j < HID; j++)
            acc[j] += xv.x * w0[j] + xv.y * w0[HID + j] + xv.z * w0[2 * HID + j] + xv.w * w0[3 * HID + j];
    }
    float s = 0.f, d = 0.f;
#pragma unroll
    for (int j = 0; j < HID; j++) {
        s += acc[j] * a_src[j];
        d += acc[j] * a_dst[j];
    }
    h8 hv0, hv1;
#pragma unroll
    for (int j = 0; j < 8; j++) { hv0[j] = (_Float16)acc[j]; hv1[j] = (_Float16)acc[8 + j]; }
    h8* hp = (h8*)(h16 + (size_t)n * HID);
    hp[0] = hv0; hp[1] = hv1;
    as_[n] = s; ad_[n] = d;
}

// ---------------- Merged gather core (round-4 structure, fp16 h):
// 16 lanes per dst, x4-unrolled serial loop. csr/as_ loads are 16-lane
// broadcasts (cheap); h is one 32B row per edge. exp computed inline
// (redundant across lanes, but proven faster than splitting passes).
__device__ __forceinline__ void gather_core(
        const unsigned short* __restrict__ row, int cnt, int j,
        const _Float16* __restrict__ h16, const float* __restrict__ as_, float adn,
        float& acc, float& den) {
    int k = 0;
    for (; k + 4 <= cnt; k += 4) {
        int s0 = row[k], s1 = row[k + 1], s2 = row[k + 2], s3 = row[k + 3];
        float l0 = as_[s0] + adn, l1 = as_[s1] + adn;
        float l2 = as_[s2] + adn, l3 = as_[s3] + adn;
        l0 = l0 > 0.f ? l0 : 0.2f * l0;
        l1 = l1 > 0.f ? l1 : 0.2f * l1;
        l2 = l2 > 0.f ? l2 : 0.2f * l2;
        l3 = l3 > 0.f ? l3 : 0.2f * l3;
        float e0 = expf(l0), e1 = expf(l1), e2 = expf(l2), e3 = expf(l3);
        float h0 = (float)h16[(size_t)s0 * HID + j];
        float h1 = (float)h16[(size_t)s1 * HID + j];
        float h2 = (float)h16[(size_t)s2 * HID + j];
        float h3 = (float)h16[(size_t)s3 * HID + j];
        den += (e0 + e1) + (e2 + e3);
        acc += (e0 * h0 + e1 * h1) + (e2 * h2 + e3 * h3);
    }
    for (; k < cnt; k++) {
        int s = row[k];
        float lg = as_[s] + adn;
        lg = lg > 0.f ? lg : 0.2f * lg;
        float e = expf(lg);
        den += e;
        acc += e * (float)h16[(size_t)s * HID + j];
    }
}

// ---------------- Fused layer-1 gather + node_h16 -> h2 fp16 + as2/ad2
__global__ void gather1_fused(const int* __restrict__ gcount, const int* __restrict__ dstbeg,
                              const unsigned short* __restrict__ csr,
                              const _Float16* __restrict__ h1,
                              const float* __restrict__ as_, const float* __restrict__ ad_,
                              const float* __restrict__ b,      // b1
                              const float* __restrict__ W2,     // [16,16]
                              const float* __restrict__ a_src2,
                              const float* __restrict__ a_dst2,
                              _Float16* __restrict__ h2,
                              float* __restrict__ as2, float* __restrict__ ad2) {
    int t = threadIdx.x;
    int j = t & 15;
    float Wcol[HID];
#pragma unroll
    for (int k = 0; k < HID; k++) Wcol[k] = W2[k * HID + j];
    float a2j = a_src2[j], d2j = a_dst2[j], bj = b[j];
    int g = blockIdx.x * (blockDim.x >> 4) + (t >> 4);
    if (g >= N_NODES) return;
    int bk = g >> 6, dl = g & 63;
    int cnt_b = gcount[bk]; if (cnt_b > CAPB) cnt_b = CAPB;
    int beg = dstbeg[g];
    int end = (dl < 63) ? dstbeg[g + 1] : cnt_b;
    if (end > cnt_b) end = cnt_b;
    if (beg > end) beg = end;
    const unsigned short* row = csr + (size_t)bk * CAPB + beg;
    float adn = ad_[g];
    float acc = 0.f, den = 0.f;
    gather_core(row, end - beg, j, h1, as_, adn, acc, den);
    // self-loop
    float lg = as_[g] + adn;
    lg = lg > 0.f ? lg : 0.2f * lg;
    float e = expf(lg);
    den += e;
    acc += e * (float)h1[(size_t)g * HID + j];
    float v = acc / den + bj;
    v = 0.5f * v * (1.f + erff(v * 0.70710678118654752f));   // x1[g][j]
    // fused node_h16: h2_j = sum_k x1_k * W2[k][j]
    float acc2 = 0.f;
#pragma unroll
    for (int k2 = 0; k2 < HID; k2++) {
        float xk = __shfl(v, k2, 16);
        acc2 += xk * Wcol[k2];
    }
    float ps = acc2 * a2j, pd = acc2 * d2j;
#pragma unroll
    for (int o = 1; o < 16; o <<= 1) {
        ps += __shfl_xor(ps, o, 16);
        pd += __shfl_xor(pd, o, 16);
    }
    h2[(size_t)g * HID + j] = (_Float16)acc2;
    if (j == 0) { as2[g] = ps; ad2[g] = pd; }
}

// ---------------- Fused layer-2 gather + edge_prep -> A/B fp16 (L2-resident)
__global__ void gather2_fused(const int* __restrict__ gcount, const int* __restrict__ dstbeg,
                              const unsigned short* __restrict__ csr,
                              const _Float16* __restrict__ h2,
                              const float* __restrict__ as_, const float* __restrict__ ad_,
                              const float* __restrict__ b,      // b2
                              const float* __restrict__ Wm1,    // [48,16] rows 0..31
                              const float* __restrict__ bm1,
                              _Float16* __restrict__ A, _Float16* __restrict__ B) {
    int t = threadIdx.x;
    int j = t & 15;
    float WaC[HID], WbC[HID];
#pragma unroll
    for (int k = 0; k < HID; k++) {
        WaC[k] = Wm1[k * HID + j];
        WbC[k] = Wm1[HID * HID + k * HID + j];
    }
    float bj = b[j], b1j = bm1[j];
    int g = blockIdx.x * (blockDim.x >> 4) + (t >> 4);
    if (g >= N_NODES) return;
    int bk = g >> 6, dl = g & 63;
    int cnt_b = gcount[bk]; if (cnt_b > CAPB) cnt_b = CAPB;
    int beg = dstbeg[g];
    int end = (dl < 63) ? dstbeg[g + 1] : cnt_b;
    if (end > cnt_b) end = cnt_b;
    if (beg > end) beg = end;
    const unsigned short* row = csr + (size_t)bk * CAPB + beg;
    float adn = ad_[g];
    float acc = 0.f, den = 0.f;
    gather_core(row, end - beg, j, h2, as_, adn, acc, den);
    // self-loop
    float lg = as_[g] + adn;
    lg = lg > 0.f ? lg : 0.2f * lg;
    float e = expf(lg);
    den += e;
    acc += e * (float)h2[(size_t)g * HID + j];
    float v = acc / den + bj;
    v = 0.5f * v * (1.f + erff(v * 0.70710678118654752f));   // x2[g][j]
    // fused edge_prep: A = x2@Wm1[0:16]+bm1, B = x2@Wm1[16:32]
    float accA = b1j, accB = 0.f;
#pragma unroll
    for (int k2 = 0; k2 < HID; k2++) {
        float xk = __shfl(v, k2, 16);
        accA += xk * WaC[k2];
        accB += xk * WbC[k2];
    }
    A[(size_t)g * HID + j] = (_Float16)accA;
    B[(size_t)g * HID + j] = (_Float16)accB;
}

// ---------------- Final per-edge MLP (round-8 proven 60.1us; weights via s_load)
__global__ void edge_mlp(const int* __restrict__ ei,
                         const _Float16* __restrict__ A, // [N,16] fp16
                         const _Float16* __restrict__ B, // [N,16] fp16
                         const float* __restrict__ ee,   // [E,16] f32
                         const float* __restrict__ Wm1,  // [48,16] (rows 32..47)
                         const float* __restrict__ Wm2,  // [16,1]
                         const float* __restrict__ bm2,  // [1]
                         float* __restrict__ out) {
    int t = threadIdx.x;
    long i = (long)blockIdx.x * blockDim.x + t;
    if (i >= N_EDGES) return;
    int s = ei[i], d = ei[N_EDGES + i];
    const h8* Ap = (const h8*)(A + (size_t)s * HID);
    const h8* Bp = (const h8*)(B + (size_t)d * HID);
    h8 a0 = Ap[0], a1 = Ap[1];
    h8 b0 = Bp[0], b1 = Bp[1];
    const float4* ep = (const float4*)(ee + (size_t)i * HID);
    float4 e0 = ep[0], e1 = ep[1], e2 = ep[2], e3 = ep[3];
    float a[HID];
#pragma unroll
    for (int j = 0; j < 8; j++) {
        a[j]     = (float)a0[j] + (float)b0[j];
        a[8 + j] = (float)a1[j] + (float)b1[j];
    }
    float ev[HID];
    ev[0]  = e0.x; ev[1]  = e0.y; ev[2]  = e0.z; ev[3]  = e0.w;
    ev[4]  = e1.x; ev[5]  = e1.y; ev[6]  = e1.z; ev[7]  = e1.w;
    ev[8]  = e2.x; ev[9]  = e2.y; ev[10] = e2.z; ev[11] = e2.w;
    ev[12] = e3.x; ev[13] = e3.y; ev[14] = e3.z; ev[15] = e3.w;
    const float4* W4 = (const float4*)(Wm1 + 2 * HID * HID);  // uniform -> s_load
#pragma unroll
    for (int k = 0; k < HID; k++) {
        float e1v = ev[k];
        float4 w0 = W4[k * 4 + 0], w1 = W4[k * 4 + 1], w2 = W4[k * 4 + 2], w3 = W4[k * 4 + 3];
        a[0]  += e1v * w0.x; a[1]  += e1v * w0.y; a[2]  += e1v * w0.z; a[3]  += e1v * w0.w;
        a[4]  += e1v * w1.x; a[5]  += e1v * w1.y; a[6]  += e1v * w1.z; a[7]  += e1v * w1.w;
        a[8]  += e1v * w2.x; a[9]  += e1v * w2.y; a[10] += e1v * w2.z; a[11] += e1v * w2.w;
        a[12] += e1v * w3.x; a[13] += e1v * w3.y; a[14] += e1v * w3.z; a[15] += e1v * w3.w;
    }
    float o = bm2[0];
#pragma unroll
    for (int j = 0; j < HID; j++) o += fmaxf(a[j], 0.f) * Wm2[j];
    out[i] = 1.f / (1.f + expf(-o));
}

extern "C" void kernel_launch(void* const* d_in, const int* in_sizes, int n_in,
                              void* d_out, int out_size, void* d_ws, size_t ws_size,
                              hipStream_t stream) {
    const int*   ei       = (const int*)d_in[0];
    const float* node_emb = (const float*)d_in[1];
    const float* edge_emb = (const float*)d_in[2];
    const float* W1       = (const float*)d_in[3];
    const float* att_src1 = (const float*)d_in[4];
    const float* att_dst1 = (const float*)d_in[5];
    const float* b1       = (const float*)d_in[6];
    const float* W2       = (const float*)d_in[7];
    const float* att_src2 = (const float*)d_in[8];
    const float* att_dst2 = (const float*)d_in[9];
    const float* b2       = (const float*)d_in[10];
    const float* Wm1      = (const float*)d_in[11];
    const float* bm1      = (const float*)d_in[12];
    const float* Wm2      = (const float*)d_in[13];
    const float* bm2      = (const float*)d_in[14];
    float* out            = (float*)d_out;

    // ---- workspace carve-up (~19 MB)
    char* w = (char*)d_ws;
    _Float16*       h1     = (_Float16*)w;       w += (size_t)N_NODES * HID * 2;      // 1.6 MB
    _Float16*       h2     = (_Float16*)w;       w += (size_t)N_NODES * HID * 2;      // 1.6 MB
    _Float16*       Anode  = (_Float16*)w;       w += (size_t)N_NODES * HID * 2;      // 1.6 MB
    _Float16*       Bnode  = (_Float16*)w;       w += (size_t)N_NODES * HID * 2;      // 1.6 MB
    float*          as1    = (float*)w;          w += (size_t)N_NODES * 4;
    float*          ad1    = (float*)w;          w += (size_t)N_NODES * 4;
    float*          as2    = (float*)w;          w += (size_t)N_NODES * 4;
    float*          ad2    = (float*)w;          w += (size_t)N_NODES * 4;
    int*            gcount = (int*)w;            w += (size_t)NBUCK * 4;
    unsigned int*   blist  = (unsigned int*)w;   w += (size_t)NBUCK * CAPB * 4;       // 8.0 MB
    unsigned short* csr    = (unsigned short*)w; w += (size_t)NBUCK * CAPB * 2;       // 4.0 MB
    int*            dstbeg = (int*)w;            w += (size_t)NBUCK * BSZ * 4;        // 0.2 MB

    const int BT = 256;
    int nblk_node = (N_NODES + BT - 1) / BT;
    int nblk_E    = (N_EDGES + BT - 1) / BT;
    int nblk_g    = (N_NODES * HID + BT - 1) / BT;   // 16 lanes per node

    // ---- 6 dispatches total (was 9): node(+zero) -> append -> sort ->
    //      gather1 -> gather2 -> edge_mlp
    node_h64<<<nblk_node, BT, 0, stream>>>(node_emb, W1, att_src1, att_dst1,
                                           h1, as1, ad1, gcount);
    append_kernel<<<APPEND_BLOCKS, APB, 0, stream>>>(ei, gcount, blist);
    sort_kernel<<<NBUCK, APB, 0, stream>>>(gcount, blist, csr, dstbeg);

    gather1_fused<<<nblk_g, BT, 0, stream>>>(gcount, dstbeg, csr, h1, as1, ad1, b1,
                                             W2, att_src2, att_dst2, h2, as2, ad2);
    gather2_fused<<<nblk_g, BT, 0, stream>>>(gcount, dstbeg, csr, h2, as2, ad2, b2,
                                             Wm1, bm1, Anode, Bnode);

    edge_mlp<<<nblk_E, BT, 0, stream>>>(ei, Anode, Bnode, edge_emb, Wm1, Wm2, bm2, out);
}

// Round 10
// 336.134 us; speedup vs baseline: 1.6948x; 1.0124x over previous
//
#include <hip/hip_runtime.h>
#include <math.h>
#include <string.h>

#define N_NODES 50000
#define N_EDGES 1600000
#define NODE_DIM 64
#define HID 16
#define BSZ 64                                // dsts per bucket
#define NBUCK ((N_NODES + BSZ - 1) / BSZ)     // 782
#define CAPB 2560                             // mean 2046, sd ~45 -> 11 sigma headroom
#define EPB 2048                              // edges per append block (782 blocks)
#define APB 256
#define APPEND_BLOCKS ((N_EDGES + EPB - 1) / EPB)   // 782
#define NODE_BLOCKS ((N_NODES + APB - 1) / APB)     // 196

typedef _Float16 h8 __attribute__((ext_vector_type(8)));

// ---------------- Fused build: blocks [0,APPEND_BLOCKS) run the aggregated
// append; blocks [APPEND_BLOCKS, +NODE_BLOCKS) run the layer-1 node transform.
// The two tasks have independent inputs/outputs -> safe to run concurrently;
// node's ~10us hides under append's ~40us. gcount zeroed by memset before.
__global__ void build_kernel(const int* __restrict__ ei,
                             int* __restrict__ gcount,
                             unsigned int* __restrict__ blist,   // [NBUCK, CAPB]
                             const float* __restrict__ x,        // [N,64]
                             const float* __restrict__ W,        // [64,16]
                             const float* __restrict__ a_src,
                             const float* __restrict__ a_dst,
                             _Float16* __restrict__ h16,         // [N,16] fp16
                             float* __restrict__ as_, float* __restrict__ ad_) {
    __shared__ int lcount[NBUCK];
    __shared__ int gbase[NBUCK];
    __shared__ int loff[NBUCK];
    int t = threadIdx.x;
    if (blockIdx.x < APPEND_BLOCKS) {
        // ---- append part (proven)
        for (int b = t; b < NBUCK; b += APB) { lcount[b] = 0; loff[b] = 0; }
        __syncthreads();
        long base = (long)blockIdx.x * EPB;
#pragma unroll
        for (int k = 0; k < EPB / APB; k++) {
            long i = base + k * APB + t;
            if (i < N_EDGES) atomicAdd(&lcount[ei[N_EDGES + i] >> 6], 1);
        }
        __syncthreads();
        for (int b = t; b < NBUCK; b += APB) {
            int c = lcount[b];
            gbase[b] = c ? atomicAdd(&gcount[b], c) : 0;
        }
        __syncthreads();
#pragma unroll
        for (int k = 0; k < EPB / APB; k++) {
            long i = base + k * APB + t;
            if (i < N_EDGES) {
                int s = ei[i], d = ei[N_EDGES + i];
                int b = d >> 6;
                int pos = gbase[b] + atomicAdd(&loff[b], 1);
                if (pos < CAPB)
                    blist[(size_t)b * CAPB + pos] = ((unsigned)(d & 63) << 16) | (unsigned)s;
            }
        }
    } else {
        // ---- node_h64 part (weights via s_load)
        int n = (blockIdx.x - APPEND_BLOCKS) * APB + t;
        if (n >= N_NODES) return;
        float acc[HID];
#pragma unroll
        for (int j = 0; j < HID; j++) acc[j] = 0.f;
        const float4* xr = (const float4*)(x + (size_t)n * NODE_DIM);
#pragma unroll
        for (int k4 = 0; k4 < NODE_DIM / 4; k4++) {
            float4 xv = xr[k4];
            const float* w0 = W + (k4 * 4) * HID;   // uniform -> s_load
#pragma unroll
            for (int j = 0; j < HID; j++)
                acc[j] += xv.x * w0[j] + xv.y * w0[HID + j] + xv.z * w0[2 * HID + j] + xv.w * w0[3 * HID + j];
        }
        float s = 0.f, d = 0.f;
#pragma unroll
        for (int j = 0; j < HID; j++) {
            s += acc[j] * a_src[j];
            d += acc[j] * a_dst[j];
        }
        h8 hv0, hv1;
#pragma unroll
        for (int j = 0; j < 8; j++) { hv0[j] = (_Float16)acc[j]; hv1[j] = (_Float16)acc[8 + j]; }
        h8* hp = (h8*)(h16 + (size_t)n * HID);
        hp[0] = hv0; hp[1] = hv1;
        as_[n] = s; ad_[n] = d;
    }
}

// ---------------- Per-bucket counting sort -> per-dst-contiguous ushort CSR.
__global__ void sort_kernel(const int* __restrict__ gcount, const unsigned int* __restrict__ blist,
                            unsigned short* __restrict__ csr, int* __restrict__ dstbeg) {
    __shared__ int cnts[BSZ];
    __shared__ int sc[BSZ];
    __shared__ int off[BSZ];
    int b = blockIdx.x, t = threadIdx.x;
    if (t < BSZ) cnts[t] = 0;
    __syncthreads();
    int cnt = gcount[b]; if (cnt > CAPB) cnt = CAPB;
    const unsigned int* lp = blist + (size_t)b * CAPB;
    for (int k = t; k < cnt; k += APB) atomicAdd(&cnts[lp[k] >> 16], 1);
    __syncthreads();
    if (t < BSZ) sc[t] = cnts[t];
    __syncthreads();
    for (int o = 1; o < BSZ; o <<= 1) {          // Hillis-Steele inclusive scan
        int v = 0;
        if (t < BSZ && t >= o) v = sc[t - o];
        __syncthreads();
        if (t < BSZ) sc[t] += v;
        __syncthreads();
    }
    if (t < BSZ) {
        int beg = sc[t] - cnts[t];               // exclusive (bucket-local)
        off[t] = beg;
        dstbeg[(b << 6) + t] = beg;
    }
    __syncthreads();
    for (int k = t; k < cnt; k += APB) {
        unsigned int r = lp[k];
        int pos = atomicAdd(&off[r >> 16], 1);
        csr[(size_t)b * CAPB + pos] = (unsigned short)(r & 0xFFFF);
    }
}

// ---------------- Gather core, x8 unroll: 16 outstanding loads per group
// (8 broadcast as_ + 8 32B h-rows), halving serial latency hops vs x4.
// The gathers are chain-latency bound (R7/R8: request-packing made them
// slower), so concurrency is the lever.
__device__ __forceinline__ void gather_core(
        const unsigned short* __restrict__ row, int cnt, int j,
        const _Float16* __restrict__ h16, const float* __restrict__ as_, float adn,
        float& acc, float& den) {
    int k = 0;
    for (; k + 8 <= cnt; k += 8) {
        int s0 = row[k],     s1 = row[k + 1], s2 = row[k + 2], s3 = row[k + 3];
        int s4 = row[k + 4], s5 = row[k + 5], s6 = row[k + 6], s7 = row[k + 7];
        float a0 = as_[s0], a1 = as_[s1], a2 = as_[s2], a3 = as_[s3];
        float a4 = as_[s4], a5 = as_[s5], a6 = as_[s6], a7 = as_[s7];
        float h0 = (float)h16[(size_t)s0 * HID + j];
        float h1 = (float)h16[(size_t)s1 * HID + j];
        float h2 = (float)h16[(size_t)s2 * HID + j];
        float h3 = (float)h16[(size_t)s3 * HID + j];
        float h4 = (float)h16[(size_t)s4 * HID + j];
        float h5 = (float)h16[(size_t)s5 * HID + j];
        float h6 = (float)h16[(size_t)s6 * HID + j];
        float h7 = (float)h16[(size_t)s7 * HID + j];
        float l0 = a0 + adn, l1 = a1 + adn, l2 = a2 + adn, l3 = a3 + adn;
        float l4 = a4 + adn, l5 = a5 + adn, l6 = a6 + adn, l7 = a7 + adn;
        l0 = l0 > 0.f ? l0 : 0.2f * l0;  l1 = l1 > 0.f ? l1 : 0.2f * l1;
        l2 = l2 > 0.f ? l2 : 0.2f * l2;  l3 = l3 > 0.f ? l3 : 0.2f * l3;
        l4 = l4 > 0.f ? l4 : 0.2f * l4;  l5 = l5 > 0.f ? l5 : 0.2f * l5;
        l6 = l6 > 0.f ? l6 : 0.2f * l6;  l7 = l7 > 0.f ? l7 : 0.2f * l7;
        float e0 = expf(l0), e1 = expf(l1), e2 = expf(l2), e3 = expf(l3);
        float e4 = expf(l4), e5 = expf(l5), e6 = expf(l6), e7 = expf(l7);
        den += ((e0 + e1) + (e2 + e3)) + ((e4 + e5) + (e6 + e7));
        acc += ((e0 * h0 + e1 * h1) + (e2 * h2 + e3 * h3))
             + ((e4 * h4 + e5 * h5) + (e6 * h6 + e7 * h7));
    }
    for (; k < cnt; k++) {
        int s = row[k];
        float lg = as_[s] + adn;
        lg = lg > 0.f ? lg : 0.2f * lg;
        float e = expf(lg);
        den += e;
        acc += e * (float)h16[(size_t)s * HID + j];
    }
}

// ---------------- Fused layer-1 gather + node_h16 -> h2 fp16 + as2/ad2
__global__ __launch_bounds__(256, 4)
void gather1_fused(const int* __restrict__ gcount, const int* __restrict__ dstbeg,
                   const unsigned short* __restrict__ csr,
                   const _Float16* __restrict__ h1,
                   const float* __restrict__ as_, const float* __restrict__ ad_,
                   const float* __restrict__ b,      // b1
                   const float* __restrict__ W2,     // [16,16]
                   const float* __restrict__ a_src2,
                   const float* __restrict__ a_dst2,
                   _Float16* __restrict__ h2,
                   float* __restrict__ as2, float* __restrict__ ad2) {
    int t = threadIdx.x;
    int j = t & 15;
    float Wcol[HID];
#pragma unroll
    for (int k = 0; k < HID; k++) Wcol[k] = W2[k * HID + j];
    float a2j = a_src2[j], d2j = a_dst2[j], bj = b[j];
    int g = blockIdx.x * (blockDim.x >> 4) + (t >> 4);
    if (g >= N_NODES) return;
    int bk = g >> 6, dl = g & 63;
    int cnt_b = gcount[bk]; if (cnt_b > CAPB) cnt_b = CAPB;
    int beg = dstbeg[g];
    int end = (dl < 63) ? dstbeg[g + 1] : cnt_b;
    if (end > cnt_b) end = cnt_b;
    if (beg > end) beg = end;
    const unsigned short* row = csr + (size_t)bk * CAPB + beg;
    float adn = ad_[g];
    float acc = 0.f, den = 0.f;
    gather_core(row, end - beg, j, h1, as_, adn, acc, den);
    // self-loop
    float lg = as_[g] + adn;
    lg = lg > 0.f ? lg : 0.2f * lg;
    float e = expf(lg);
    den += e;
    acc += e * (float)h1[(size_t)g * HID + j];
    float v = acc / den + bj;
    v = 0.5f * v * (1.f + erff(v * 0.70710678118654752f));   // x1[g][j]
    // fused node_h16: h2_j = sum_k x1_k * W2[k][j]
    float acc2 = 0.f;
#pragma unroll
    for (int k2 = 0; k2 < HID; k2++) {
        float xk = __shfl(v, k2, 16);
        acc2 += xk * Wcol[k2];
    }
    float ps = acc2 * a2j, pd = acc2 * d2j;
#pragma unroll
    for (int o = 1; o < 16; o <<= 1) {
        ps += __shfl_xor(ps, o, 16);
        pd += __shfl_xor(pd, o, 16);
    }
    h2[(size_t)g * HID + j] = (_Float16)acc2;
    if (j == 0) { as2[g] = ps; ad2[g] = pd; }
}

// ---------------- Fused layer-2 gather + edge_prep -> A/B fp16 (L2-resident)
__global__ __launch_bounds__(256, 4)
void gather2_fused(const int* __restrict__ gcount, const int* __restrict__ dstbeg,
                   const unsigned short* __restrict__ csr,
                   const _Float16* __restrict__ h2,
                   const float* __restrict__ as_, const float* __restrict__ ad_,
                   const float* __restrict__ b,      // b2
                   const float* __restrict__ Wm1,    // [48,16] rows 0..31
                   const float* __restrict__ bm1,
                   _Float16* __restrict__ A, _Float16* __restrict__ B) {
    int t = threadIdx.x;
    int j = t & 15;
    float WaC[HID], WbC[HID];
#pragma unroll
    for (int k = 0; k < HID; k++) {
        WaC[k] = Wm1[k * HID + j];
        WbC[k] = Wm1[HID * HID + k * HID + j];
    }
    float bj = b[j], b1j = bm1[j];
    int g = blockIdx.x * (blockDim.x >> 4) + (t >> 4);
    if (g >= N_NODES) return;
    int bk = g >> 6, dl = g & 63;
    int cnt_b = gcount[bk]; if (cnt_b > CAPB) cnt_b = CAPB;
    int beg = dstbeg[g];
    int end = (dl < 63) ? dstbeg[g + 1] : cnt_b;
    if (end > cnt_b) end = cnt_b;
    if (beg > end) beg = end;
    const unsigned short* row = csr + (size_t)bk * CAPB + beg;
    float adn = ad_[g];
    float acc = 0.f, den = 0.f;
    gather_core(row, end - beg, j, h2, as_, adn, acc, den);
    // self-loop
    float lg = as_[g] + adn;
    lg = lg > 0.f ? lg : 0.2f * lg;
    float e = expf(lg);
    den += e;
    acc += e * (float)h2[(size_t)g * HID + j];
    float v = acc / den + bj;
    v = 0.5f * v * (1.f + erff(v * 0.70710678118654752f));   // x2[g][j]
    // fused edge_prep: A = x2@Wm1[0:16]+bm1, B = x2@Wm1[16:32]
    float accA = b1j, accB = 0.f;
#pragma unroll
    for (int k2 = 0; k2 < HID; k2++) {
        float xk = __shfl(v, k2, 16);
        accA += xk * WaC[k2];
        accB += xk * WbC[k2];
    }
    A[(size_t)g * HID + j] = (_Float16)accA;
    B[(size_t)g * HID + j] = (_Float16)accB;
}

// ---------------- Final per-edge MLP. launch_bounds(256,4) lifts the VGPR
// cap from the compiler-chosen 24 (which serialized the 8 loads ->
// 2-3 outstanding requests/wave) to 128: all A/B/ee loads in flight.
__global__ __launch_bounds__(256, 4)
void edge_mlp(const int* __restrict__ ei,
              const _Float16* __restrict__ A, // [N,16] fp16
              const _Float16* __restrict__ B, // [N,16] fp16
              const float* __restrict__ ee,   // [E,16] f32
              const float* __restrict__ Wm1,  // [48,16] (rows 32..47)
              const float* __restrict__ Wm2,  // [16,1]
              const float* __restrict__ bm2,  // [1]
              float* __restrict__ out) {
    int t = threadIdx.x;
    long i = (long)blockIdx.x * blockDim.x + t;
    if (i >= N_EDGES) return;
    int s = ei[i], d = ei[N_EDGES + i];
    const h8* Ap = (const h8*)(A + (size_t)s * HID);
    const h8* Bp = (const h8*)(B + (size_t)d * HID);
    const float4* ep = (const float4*)(ee + (size_t)i * HID);
    // all 8 loads issued before any use
    h8 a0 = Ap[0], a1 = Ap[1];
    h8 b0 = Bp[0], b1 = Bp[1];
    float4 e0 = ep[0], e1 = ep[1], e2 = ep[2], e3 = ep[3];
    float a[HID];
#pragma unroll
    for (int j = 0; j < 8; j++) {
        a[j]     = (float)a0[j] + (float)b0[j];
        a[8 + j] = (float)a1[j] + (float)b1[j];
    }
    float ev[HID];
    ev[0]  = e0.x; ev[1]  = e0.y; ev[2]  = e0.z; ev[3]  = e0.w;
    ev[4]  = e1.x; ev[5]  = e1.y; ev[6]  = e1.z; ev[7]  = e1.w;
    ev[8]  = e2.x; ev[9]  = e2.y; ev[10] = e2.z; ev[11] = e2.w;
    ev[12] = e3.x; ev[13] = e3.y; ev[14] = e3.z; ev[15] = e3.w;
    const float4* W4 = (const float4*)(Wm1 + 2 * HID * HID);  // uniform -> s_load
#pragma unroll
    for (int k = 0; k < HID; k++) {
        float e1v = ev[k];
        float4 w0 = W4[k * 4 + 0], w1 = W4[k * 4 + 1], w2 = W4[k * 4 + 2], w3 = W4[k * 4 + 3];
        a[0]  += e1v * w0.x; a[1]  += e1v * w0.y; a[2]  += e1v * w0.z; a[3]  += e1v * w0.w;
        a[4]  += e1v * w1.x; a[5]  += e1v * w1.y; a[6]  += e1v * w1.z; a[7]  += e1v * w1.w;
        a[8]  += e1v * w2.x; a[9]  += e1v * w2.y; a[10] += e1v * w2.z; a[11] += e1v * w2.w;
        a[12] += e1v * w3.x; a[13] += e1v * w3.y; a[14] += e1v * w3.z; a[15] += e1v * w3.w;
    }
    float o = bm2[0];
#pragma unroll
    for (int j = 0; j < HID; j++) o += fmaxf(a[j], 0.f) * Wm2[j];
    out[i] = 1.f / (1.f + expf(-o));
}

extern "C" void kernel_launch(void* const* d_in, const int* in_sizes, int n_in,
                              void* d_out, int out_size, void* d_ws, size_t ws_size,
                              hipStream_t stream) {
    const int*   ei       = (const int*)d_in[0];
    const float* node_emb = (const float*)d_in[1];
    const float* edge_emb = (const float*)d_in[2];
    const float* W1       = (const float*)d_in[3];
    const float* att_src1 = (const float*)d_in[4];
    const float* att_dst1 = (const float*)d_in[5];
    const float* b1       = (const float*)d_in[6];
    const float* W2       = (const float*)d_in[7];
    const float* att_src2 = (const float*)d_in[8];
    const float* att_dst2 = (const float*)d_in[9];
    const float* b2       = (const float*)d_in[10];
    const float* Wm1      = (const float*)d_in[11];
    const float* bm1      = (const float*)d_in[12];
    const float* Wm2      = (const float*)d_in[13];
    const float* bm2      = (const float*)d_in[14];
    float* out            = (float*)d_out;

    // ---- workspace carve-up (~19 MB)
    char* w = (char*)d_ws;
    _Float16*       h1     = (_Float16*)w;       w += (size_t)N_NODES * HID * 2;      // 1.6 MB
    _Float16*       h2     = (_Float16*)w;       w += (size_t)N_NODES * HID * 2;      // 1.6 MB
    _Float16*       Anode  = (_Float16*)w;       w += (size_t)N_NODES * HID * 2;      // 1.6 MB
    _Float16*       Bnode  = (_Float16*)w;       w += (size_t)N_NODES * HID * 2;      // 1.6 MB
    float*          as1    = (float*)w;          w += (size_t)N_NODES * 4;
    float*          ad1    = (float*)w;          w += (size_t)N_NODES * 4;
    float*          as2    = (float*)w;          w += (size_t)N_NODES * 4;
    float*          ad2    = (float*)w;          w += (size_t)N_NODES * 4;
    int*            gcount = (int*)w;            w += (size_t)NBUCK * 4;
    unsigned int*   blist  = (unsigned int*)w;   w += (size_t)NBUCK * CAPB * 4;       // 8.0 MB
    unsigned short* csr    = (unsigned short*)w; w += (size_t)NBUCK * CAPB * 2;       // 4.0 MB
    int*            dstbeg = (int*)w;            w += (size_t)NBUCK * BSZ * 4;        // 0.2 MB

    const int BT = 256;
    int nblk_E    = (N_EDGES + BT - 1) / BT;
    int nblk_g    = (N_NODES * HID + BT - 1) / BT;   // 16 lanes per node

    // ---- 6 dispatches: memset -> build(node || append) -> sort ->
    //      gather1 -> gather2 -> edge_mlp
    hipMemsetAsync(gcount, 0, (size_t)NBUCK * sizeof(int), stream);
    build_kernel<<<APPEND_BLOCKS + NODE_BLOCKS, APB, 0, stream>>>(
        ei, gcount, blist, node_emb, W1, att_src1, att_dst1, h1, as1, ad1);
    sort_kernel<<<NBUCK, APB, 0, stream>>>(gcount, blist, csr, dstbeg);

    gather1_fused<<<nblk_g, BT, 0, stream>>>(gcount, dstbeg, csr, h1, as1, ad1, b1,
                                             W2, att_src2, att_dst2, h2, as2, ad2);
    gather2_fused<<<nblk_g, BT, 0, stream>>>(gcount, dstbeg, csr, h2, as2, ad2, b2,
                                             Wm1, bm1, Anode, Bnode);

    edge_mlp<<<nblk_E, BT, 0, stream>>>(ei, Anode, Bnode, edge_emb, Wm1, Wm2, bm2, out);
}